// Round 4
// baseline (59629.279 us; speedup 1.0000x reference)
//
#include <hip/hip_runtime.h>
#include <stdint.h>

// HistMatching via stable LSD radix sort (4 x 8-bit passes) of (key32,idx32)
// u64 pairs per segment -- ONESWEEP edition.
// R4 changes vs R3:
//  - hist_k / transpose / 3-level scan deleted; global per-digit CDFs for all
//    4 passes are computed once in init_k (order-independent).
//  - part_k passes use ticketed decoupled lookback (device-scope atomics) for
//    per-block stable bases: single read of the pairs array per pass.
//    Ticket order == tile order => stability; tickets make lookback safe under
//    arbitrary workgroup dispatch order (predecessor has always started).
//  - TILE 4096 -> 2560: LDS ~47KB -> 3 blocks/CU (occupancy 17% -> ~25%).

#define SEG_N 2621440            // 128*160*128
#define NSEG 9                   // template + 8 samples
#define TILE 2560
#define EPT 10                   // elements per thread (256 thr)
#define NBLK (SEG_N / TILE)      // 1024 blocks per segment
#define RADIX 256
#define SB (TILE + (TILE >> 4))  // padded LDS tile (u64)
#define STSEG (NBLK * RADIX)     // status words per segment per pass
#define VMASK 0x3FFFFFFFu

// monotone f32 -> u32 (order-preserving)
__device__ __forceinline__ uint32_t fkey(float f) {
  uint32_t b = __float_as_uint(f);
  return b ^ ((b & 0x80000000u) ? 0xFFFFFFFFu : 0x80000000u);
}
__device__ __forceinline__ float finv(uint32_t u) {
  uint32_t b = u ^ ((u & 0x80000000u) ? 0x80000000u : 0xFFFFFFFFu);
  return __uint_as_float(b);
}
__device__ __forceinline__ uint32_t SIDX(uint32_t i) { return i + (i >> 4); }

// ---------- init: build pairs (index order) + global hists for all 4 digits ----------
__global__ __launch_bounds__(256) void init_k(const float* __restrict__ x,
                                              const float* __restrict__ tmpl,
                                              int segbase,
                                              uint64_t* __restrict__ pairsA,
                                              uint32_t* __restrict__ gh) {
  __shared__ uint32_t h[1024];
  const int t = threadIdx.x;
  const int blk = blockIdx.x, sl = blockIdx.y;
  const int seg = segbase + sl;
  const float* src = (seg == 0) ? tmpl : (x + (size_t)(seg - 1) * SEG_N);
  uint64_t* pa = pairsA + (size_t)sl * SEG_N;
  for (int i = t; i < 1024; i += 256) h[i] = 0;
  __syncthreads();
  const uint32_t base = blk * TILE;
#pragma unroll
  for (int r = 0; r < EPT; ++r) {
    uint32_t i = base + r * 256u + t;
    uint32_t k = fkey(src[i]);
    pa[i] = ((uint64_t)k << 32) | (uint64_t)i;
    atomicAdd(&h[k & 255u], 1u);
    atomicAdd(&h[256 + ((k >> 8) & 255u)], 1u);
    atomicAdd(&h[512 + ((k >> 16) & 255u)], 1u);
    atomicAdd(&h[768 + (k >> 24)], 1u);
  }
  __syncthreads();
  for (int i = t; i < 1024; i += 256)
    if (h[i]) atomicAdd(&gh[(size_t)sl * 1024 + i], h[i]);
}

// ---------- in-place exclusive scan of each 256-bin histogram ----------
__global__ __launch_bounds__(256) void cdf_k(uint32_t* __restrict__ gh) {
  __shared__ uint32_t lds[256];
  const int t = threadIdx.x;
  uint32_t* p = gh + ((size_t)blockIdx.y * 4 + blockIdx.x) * 256;
  uint32_t v = p[t];
  lds[t] = v;
  __syncthreads();
#pragma unroll
  for (int off = 1; off < 256; off <<= 1) {
    uint32_t a = (t >= off) ? lds[t - off] : 0u;
    __syncthreads();
    lds[t] += a;
    __syncthreads();
  }
  p[t] = lds[t] - v;  // exclusive
}

// ---------- dual packed-u16 exclusive scan over 256 threads ----------
__device__ __forceinline__ void scan_pack2(uint32_t v0, uint32_t v1, uint32_t* s,
                                           uint32_t& ex0, uint32_t& ex1,
                                           uint32_t& tot0, uint32_t& tot1) {
  const int lane = threadIdx.x & 63, w = threadIdx.x >> 6;
  uint32_t a = v0, b = v1;
#pragma unroll
  for (int o = 1; o < 64; o <<= 1) {
    uint32_t na = __shfl_up(a, (unsigned)o, 64);
    uint32_t nb = __shfl_up(b, (unsigned)o, 64);
    if (lane >= o) { a += na; b += nb; }
  }
  if (lane == 63) { s[w] = a; s[4 + w] = b; }
  __syncthreads();
  if (threadIdx.x == 0) {
    uint32_t r0 = 0, r1 = 0;
#pragma unroll
    for (int i = 0; i < 4; ++i) {
      uint32_t q0 = s[i], q1 = s[4 + i];
      s[i] = r0; s[4 + i] = r1;
      r0 += q0; r1 += q1;
    }
    s[8] = r0; s[9] = r1;
  }
  __syncthreads();
  ex0 = a - v0 + s[w];
  ex1 = b - v1 + s[4 + w];
  tot0 = s[8]; tot1 = s[9];
  __syncthreads();
}

// ---------- onesweep partition pass (digit P, output MODE) ----------
// MODE 0: dst pairs; MODE 1: tsorted[dest]=val; MODE 2: out[idx]=tsorted[dest]
template <int P, int MODE>
__global__ __launch_bounds__(256) void part_k(const uint64_t* __restrict__ src,
                                              uint64_t* __restrict__ dst,
                                              uint32_t* __restrict__ st,
                                              const uint32_t* __restrict__ gh,
                                              uint32_t* __restrict__ tick,
                                              float* __restrict__ tsorted,
                                              float* __restrict__ out,
                                              int segbase, int slbase) {
  __shared__ uint64_t bufA[SB];
  __shared__ uint64_t bufB[SB];
  __shared__ uint32_t ldsHist[RADIX];
  __shared__ uint32_t ldsStart[RADIX];
  __shared__ uint32_t ldsBase[RADIX];
  __shared__ uint32_t scanS[12];
  __shared__ uint32_t tkS;
  const int t = threadIdx.x;
  const int sl = slbase + blockIdx.y;
  const int seg = segbase + sl;

  // ticket = logical block id (defines tile AND lookback order)
  if (t == 0)
    tkS = __hip_atomic_fetch_add(&tick[sl], 1u, __ATOMIC_RELAXED,
                                 __HIP_MEMORY_SCOPE_AGENT);
  __syncthreads();
  const uint32_t blk = tkS;
  uint32_t* stS = st + (size_t)sl * STSEG;  // [blk][digit] for this pass

  // stage tile into LDS (coalesced)
  const uint64_t* ps = src + (size_t)sl * SEG_N + (size_t)blk * TILE;
#pragma unroll
  for (int r = 0; r < EPT; ++r) bufA[SIDX(r * 256 + t)] = ps[r * 256 + t];
  ldsHist[t] = 0;
  __syncthreads();

  // thread-major elements (stability order), digit histogram
  uint64_t e[EPT];
#pragma unroll
  for (int j = 0; j < EPT; ++j) e[j] = bufA[SIDX(t * EPT + j)];
#pragma unroll
  for (int j = 0; j < EPT; ++j)
    atomicAdd(&ldsHist[(uint32_t)(e[j] >> (32 + 8 * P)) & 255u], 1u);
  __syncthreads();

  // publish aggregate EARLY (before the split work) -> short lookback windows
  const uint32_t agg = ldsHist[t];
  __hip_atomic_store(&stS[(size_t)blk * RADIX + t], agg | 0x40000000u,
                     __ATOMIC_RELEASE, __HIP_MEMORY_SCOPE_AGENT);

  // 4 stable 2-bit split rounds: A->B->A->B->A
  uint64_t* cur = bufA;
  uint64_t* nxt = bufB;
#pragma unroll
  for (int rnd = 0; rnd < 4; ++rnd) {
    if (rnd) {
#pragma unroll
      for (int j = 0; j < EPT; ++j) e[j] = cur[SIDX(t * EPT + j)];
    }
    uint32_t cnt[4] = {0u, 0u, 0u, 0u};
#pragma unroll
    for (int j = 0; j < EPT; ++j)
      cnt[(uint32_t)(e[j] >> (32 + 8 * P + 2 * rnd)) & 3u]++;
    uint32_t ex0, ex1, tot0, tot1;
    scan_pack2(cnt[0] | (cnt[1] << 16), cnt[2] | (cnt[3] << 16), scanS, ex0, ex1,
               tot0, tot1);
    uint32_t t0 = tot0 & 0xffffu, t1 = tot0 >> 16, t2 = tot1 & 0xffffu;
    uint32_t pos[4];
    pos[0] = (ex0 & 0xffffu);
    pos[1] = t0 + (ex0 >> 16);
    pos[2] = t0 + t1 + (ex1 & 0xffffu);
    pos[3] = t0 + t1 + t2 + (ex1 >> 16);
#pragma unroll
    for (int j = 0; j < EPT; ++j) {
      uint32_t d2 = (uint32_t)(e[j] >> (32 + 8 * P + 2 * rnd)) & 3u;
      nxt[SIDX(pos[d2]++)] = e[j];
    }
    __syncthreads();
    uint64_t* tmp = cur; cur = nxt; nxt = tmp;
  }
  // cur == bufA: tile stably sorted by digit P

  // local exclusive starts per digit (scan of ldsHist)
  {
    uint32_t v = agg;
    const int lane = t & 63, w = t >> 6;
    uint32_t s = v;
#pragma unroll
    for (int o = 1; o < 64; o <<= 1) {
      uint32_t n = __shfl_up(s, (unsigned)o, 64);
      if (lane >= o) s += n;
    }
    if (lane == 63) scanS[8 + w] = s;
    __syncthreads();
    if (t == 0) {
      uint32_t a = 0;
#pragma unroll
      for (int i = 0; i < 4; ++i) { uint32_t q = scanS[8 + i]; scanS[8 + i] = a; a += q; }
    }
    __syncthreads();
    ldsStart[t] = s - v + scanS[8 + w];
  }

  // decoupled lookback (batched, thread t owns digit t)
  {
    uint32_t ex = 0;
    int p = (int)blk - 1;
    while (p >= 0) {
      uint32_t vs[8];
      const int n = (p + 1 < 8) ? p + 1 : 8;
      bool retry = true;
      while (retry) {
        retry = false;
        for (int i = 0; i < n; ++i)
          vs[i] = __hip_atomic_load(&stS[(size_t)(p - i) * RADIX + t],
                                    __ATOMIC_ACQUIRE, __HIP_MEMORY_SCOPE_AGENT);
        for (int i = 0; i < n; ++i)
          if ((vs[i] >> 30) == 0) retry = true;
        if (retry) __builtin_amdgcn_s_sleep(4);
      }
      bool hit_inc = false;
      for (int i = 0; i < n; ++i) {
        ex += vs[i] & VMASK;
        if ((vs[i] >> 30) >= 2) { hit_inc = true; break; }
      }
      if (hit_inc) break;
      p -= n;
    }
    __hip_atomic_store(&stS[(size_t)blk * RADIX + t], (agg + ex) | 0x80000000u,
                       __ATOMIC_RELEASE, __HIP_MEMORY_SCOPE_AGENT);
    ldsBase[t] = gh[((size_t)sl * 4 + P) * 256 + t] + ex;
  }
  __syncthreads();

  // emit in sorted-tile order: digit runs -> contiguous global ranges
#pragma unroll
  for (int r = 0; r < EPT; ++r) {
    uint32_t s = (uint32_t)(r * 256 + t);
    uint64_t el = cur[SIDX(s)];
    uint32_t d = (uint32_t)(el >> (32 + 8 * P)) & 255u;
    uint32_t dest = ldsBase[d] + s - ldsStart[d];
    if (MODE == 0) {
      dst[(size_t)sl * SEG_N + dest] = el;
    } else if (MODE == 1) {
      tsorted[dest] = finv((uint32_t)(el >> 32));
    } else {
      out[(size_t)(seg - 1) * SEG_N + (uint32_t)el] = tsorted[dest];
    }
  }
}

// ---------------------------------------------------------------------------
extern "C" void kernel_launch(void* const* d_in, const int* in_sizes, int n_in,
                              void* d_out, int out_size, void* d_ws, size_t ws_size,
                              hipStream_t stream) {
  const float* x = (const float*)d_in[0];
  const float* tmpl = (const float*)d_in[1];
  float* out = (float*)d_out;

  auto needB = [](int nb) -> size_t {
    return (size_t)nb * SEG_N * 16 + (size_t)nb * STSEG * 4 +
           (size_t)nb * 1024 * 4 + (size_t)nb * 4 * 4 + (size_t)SEG_N * 4 + 65536;
  };
  const int nb = (ws_size >= needB(9)) ? 9 : (ws_size >= needB(3)) ? 3 : 1;

  uint8_t* w = (uint8_t*)d_ws;
  size_t off = 0;
  auto carve = [&](size_t bytes) -> void* {
    void* p = w + off;
    off = (off + bytes + 255) & ~(size_t)255;
    return p;
  };
  uint64_t* pairsA = (uint64_t*)carve((size_t)nb * SEG_N * 8);
  uint64_t* pairsB = (uint64_t*)carve((size_t)nb * SEG_N * 8);
  uint32_t* st = (uint32_t*)carve((size_t)nb * STSEG * 4);
  uint32_t* gh = (uint32_t*)carve((size_t)nb * 1024 * 4);
  uint32_t* tick = (uint32_t*)carve((size_t)nb * 4 * 4);  // [pass][sl]
  float* tsorted = (float*)carve((size_t)SEG_N * 4);

  const size_t stBytes = (size_t)nb * STSEG * 4;

  for (int g = 0; g < NSEG; g += nb) {
    hipMemsetAsync(gh, 0, (size_t)nb * 1024 * 4, stream);
    hipMemsetAsync(tick, 0, (size_t)nb * 4 * 4, stream);

    init_k<<<dim3(NBLK, nb), 256, 0, stream>>>(x, tmpl, g, pairsA, gh);
    cdf_k<<<dim3(4, nb), 256, 0, stream>>>(gh);

    hipMemsetAsync(st, 0, stBytes, stream);
    part_k<0, 0><<<dim3(NBLK, nb), 256, 0, stream>>>(pairsA, pairsB, st, gh,
                                                     tick + 0 * nb, tsorted, out, g, 0);
    hipMemsetAsync(st, 0, stBytes, stream);
    part_k<1, 0><<<dim3(NBLK, nb), 256, 0, stream>>>(pairsB, pairsA, st, gh,
                                                     tick + 1 * nb, tsorted, out, g, 0);
    hipMemsetAsync(st, 0, stBytes, stream);
    part_k<2, 0><<<dim3(NBLK, nb), 256, 0, stream>>>(pairsA, pairsB, st, gh,
                                                     tick + 2 * nb, tsorted, out, g, 0);
    hipMemsetAsync(st, 0, stBytes, stream);
    if (g == 0) {
      part_k<3, 1><<<dim3(NBLK, 1), 256, 0, stream>>>(pairsB, pairsA, st, gh,
                                                      tick + 3 * nb, tsorted, out, g, 0);
      if (nb > 1)
        part_k<3, 2><<<dim3(NBLK, nb - 1), 256, 0, stream>>>(pairsB, pairsA, st, gh,
                                                             tick + 3 * nb, tsorted, out, g, 1);
    } else {
      part_k<3, 2><<<dim3(NBLK, nb), 256, 0, stream>>>(pairsB, pairsA, st, gh,
                                                       tick + 3 * nb, tsorted, out, g, 0);
    }
  }
}

// Round 5
// 1356.111 us; speedup vs baseline: 43.9708x; 43.9708x over previous
//
#include <hip/hip_runtime.h>
#include <stdint.h>

// HistMatching via stable LSD radix sort (4 x 8-bit passes) of (key32,idx32)
// u64 pairs per segment. Two-phase per pass: per-(block,bin) histogram ->
// per-bin exclusive scan over blocks -> stable LDS partition.
// R5 vs R3:
//  - global per-digit CDFs for all 4 passes computed once in init_k (order-
//    independent) + one cdf_k; per-pass base scan is a single binscan_k
//    (transp/scan_a/scan_b/scan_c deleted; 24 -> 16 dispatches).
//  - TILE 4096 -> 2048: part_k LDS ~38KB -> 4 blocks/CU (occupancy 17 -> ~33%).
//  - per-wave replicated LDS histograms in init/hist (fewer LDS-atomic stalls).
// R4's decoupled lookback removed: cross-XCD spin-wait collapsed (114ms/dispatch).

#define SEG_N 2621440            // 128*160*128
#define NSEG 9                   // template + 8 samples
#define TILE 2048
#define EPT 8                    // elements per thread (256 thr)
#define NBLK (SEG_N / TILE)      // 1280 blocks per segment
#define RADIX 256
#define HL (RADIX * NBLK)        // per-seg histogram matrix entries
#define SB (TILE + (TILE >> 4))  // padded LDS tile (u64)

// monotone f32 -> u32 (order-preserving)
__device__ __forceinline__ uint32_t fkey(float f) {
  uint32_t b = __float_as_uint(f);
  return b ^ ((b & 0x80000000u) ? 0xFFFFFFFFu : 0x80000000u);
}
__device__ __forceinline__ float finv(uint32_t u) {
  uint32_t b = u ^ ((u & 0x80000000u) ? 0x80000000u : 0xFFFFFFFFu);
  return __uint_as_float(b);
}
__device__ __forceinline__ uint32_t SIDX(uint32_t i) { return i + (i >> 4); }

// ---------- init: pairs (index order) + per-block digit0 hist + global 4-digit hists ----------
__global__ __launch_bounds__(256) void init_k(const float* __restrict__ x,
                                              const float* __restrict__ tmpl,
                                              int segbase,
                                              uint64_t* __restrict__ pairsA,
                                              uint32_t* __restrict__ Hkb,
                                              uint32_t* __restrict__ gh) {
  __shared__ uint32_t h[4][1024];  // per-wave replicas
  const int t = threadIdx.x;
  const int w = t >> 6;
  const int blk = blockIdx.x, sl = blockIdx.y;
  const int seg = segbase + sl;
  const float* src = (seg == 0) ? tmpl : (x + (size_t)(seg - 1) * SEG_N);
  uint64_t* pa = pairsA + (size_t)sl * SEG_N;
  for (int i = t; i < 4096; i += 256) ((uint32_t*)h)[i] = 0;
  __syncthreads();
  const uint32_t base = blk * TILE;
#pragma unroll
  for (int r = 0; r < EPT; ++r) {
    uint32_t i = base + r * 256u + t;
    uint32_t k = fkey(src[i]);
    pa[i] = ((uint64_t)k << 32) | (uint64_t)i;
    atomicAdd(&h[w][k & 255u], 1u);
    atomicAdd(&h[w][256 + ((k >> 8) & 255u)], 1u);
    atomicAdd(&h[w][512 + ((k >> 16) & 255u)], 1u);
    atomicAdd(&h[w][768 + (k >> 24)], 1u);
  }
  __syncthreads();
  for (int i = t; i < 1024; i += 256) {
    uint32_t s = h[0][i] + h[1][i] + h[2][i] + h[3][i];
    if (s) atomicAdd(&gh[(size_t)sl * 1024 + i], s);
    if (i < 256) Hkb[(size_t)sl * HL + (size_t)blk * RADIX + i] = s;  // digit-0
  }
}

// ---------- per-(block,bin) histogram of digit p (coalesced [blk][bin] write) ----------
__global__ __launch_bounds__(256) void hist_k(const uint64_t* __restrict__ pairs,
                                              uint32_t* __restrict__ Hkb, int p) {
  __shared__ uint32_t h[4][RADIX];
  const int t = threadIdx.x;
  const int w = t >> 6;
  const int blk = blockIdx.x, sl = blockIdx.y;
  const uint64_t* pc = pairs + (size_t)sl * SEG_N + (size_t)blk * TILE;
  for (int i = t; i < 1024; i += 256) ((uint32_t*)h)[i] = 0;
  __syncthreads();
  const int sh = 32 + 8 * p;
#pragma unroll
  for (int r = 0; r < EPT; ++r) {
    uint64_t e = pc[r * 256 + t];
    atomicAdd(&h[w][(uint32_t)(e >> sh) & 255u], 1u);
  }
  __syncthreads();
  Hkb[(size_t)sl * HL + (size_t)blk * RADIX + t] =
      h[0][t] + h[1][t] + h[2][t] + h[3][t];
}

// ---------- shared block-scan helper ----------
__device__ __forceinline__ uint32_t block_excl_scan_256(uint32_t v, uint32_t* lds) {
  const int t = threadIdx.x;
  lds[t] = v;
  __syncthreads();
#pragma unroll
  for (int off = 1; off < 256; off <<= 1) {
    uint32_t a = (t >= off) ? lds[t - off] : 0u;
    __syncthreads();
    lds[t] += a;
    __syncthreads();
  }
  uint32_t ex = (t == 0) ? 0u : lds[t - 1];
  __syncthreads();
  return ex;
}

// ---------- exclusive scan of each 256-bin global histogram (in place) ----------
__global__ __launch_bounds__(256) void cdf_k(uint32_t* __restrict__ gh) {
  __shared__ uint32_t lds[256];
  const int t = threadIdx.x;
  uint32_t* p = gh + ((size_t)blockIdx.y * 4 + blockIdx.x) * 256;
  uint32_t v = p[t];
  p[t] = block_excl_scan_256(v, lds) ;
}

// ---------- per-bin exclusive scan over 1280 block counts (in place) ----------
__global__ __launch_bounds__(256) void binscan_k(uint32_t* __restrict__ Hkb) {
  __shared__ uint32_t lds[256];
  const int t = threadIdx.x;
  const int bin = blockIdx.x, sl = blockIdx.y;
  uint32_t* base = Hkb + (size_t)sl * HL + bin;
  uint32_t v[5];
  uint32_t s = 0;
#pragma unroll
  for (int j = 0; j < 5; ++j) {
    v[j] = base[(size_t)(t * 5 + j) * RADIX];
    s += v[j];
  }
  uint32_t ex = block_excl_scan_256(s, lds);
#pragma unroll
  for (int j = 0; j < 5; ++j) {
    base[(size_t)(t * 5 + j) * RADIX] = ex;
    ex += v[j];
  }
}

// ---------- dual packed-u16 exclusive scan over 256 threads ----------
__device__ __forceinline__ void scan_pack2(uint32_t v0, uint32_t v1, uint32_t* s,
                                           uint32_t& ex0, uint32_t& ex1,
                                           uint32_t& tot0, uint32_t& tot1) {
  const int lane = threadIdx.x & 63, w = threadIdx.x >> 6;
  uint32_t a = v0, b = v1;
#pragma unroll
  for (int o = 1; o < 64; o <<= 1) {
    uint32_t na = __shfl_up(a, (unsigned)o, 64);
    uint32_t nb = __shfl_up(b, (unsigned)o, 64);
    if (lane >= o) { a += na; b += nb; }
  }
  if (lane == 63) { s[w] = a; s[4 + w] = b; }
  __syncthreads();
  if (threadIdx.x == 0) {
    uint32_t r0 = 0, r1 = 0;
#pragma unroll
    for (int i = 0; i < 4; ++i) {
      uint32_t q0 = s[i], q1 = s[4 + i];
      s[i] = r0; s[4 + i] = r1;
      r0 += q0; r1 += q1;
    }
    s[8] = r0; s[9] = r1;
  }
  __syncthreads();
  ex0 = a - v0 + s[w];
  ex1 = b - v1 + s[4 + w];
  tot0 = s[8]; tot1 = s[9];
  __syncthreads();
}

// ---------- stable partition pass (digit P, output MODE) ----------
// MODE 0: dst pairs; MODE 1: tsorted[dest]=val; MODE 2: out[idx]=tsorted[dest]
template <int P, int MODE>
__global__ __launch_bounds__(256) void part_k(const uint64_t* __restrict__ src,
                                              uint64_t* __restrict__ dst,
                                              const uint32_t* __restrict__ Hkb,
                                              const uint32_t* __restrict__ gh,
                                              float* __restrict__ tsorted,
                                              float* __restrict__ out,
                                              int segbase, int slbase) {
  __shared__ uint64_t bufA[SB];
  __shared__ uint64_t bufB[SB];
  __shared__ uint32_t ldsHist[RADIX];
  __shared__ uint32_t ldsStart[RADIX];
  __shared__ uint32_t ldsBase[RADIX];
  __shared__ uint32_t scanS[12];
  const int t = threadIdx.x;
  const int blk = blockIdx.x;
  const int sl = slbase + blockIdx.y;
  const int seg = segbase + sl;
  const uint64_t* ps = src + (size_t)sl * SEG_N + (size_t)blk * TILE;

  // stage tile into LDS (coalesced)
#pragma unroll
  for (int r = 0; r < EPT; ++r) bufA[SIDX(r * 256 + t)] = ps[r * 256 + t];
  ldsHist[t] = 0;
  __syncthreads();

  // 4 stable 2-bit split rounds: A->B->A->B->A
  uint64_t e[EPT];
  uint64_t* cur = bufA;
  uint64_t* nxt = bufB;
#pragma unroll
  for (int rnd = 0; rnd < 4; ++rnd) {
#pragma unroll
    for (int j = 0; j < EPT; ++j) e[j] = cur[SIDX(t * EPT + j)];
    uint32_t cnt[4] = {0u, 0u, 0u, 0u};
#pragma unroll
    for (int j = 0; j < EPT; ++j)
      cnt[(uint32_t)(e[j] >> (32 + 8 * P + 2 * rnd)) & 3u]++;
    uint32_t ex0, ex1, tot0, tot1;
    scan_pack2(cnt[0] | (cnt[1] << 16), cnt[2] | (cnt[3] << 16), scanS, ex0, ex1,
               tot0, tot1);
    uint32_t t0 = tot0 & 0xffffu, t1 = tot0 >> 16, t2 = tot1 & 0xffffu;
    uint32_t pos[4];
    pos[0] = (ex0 & 0xffffu);
    pos[1] = t0 + (ex0 >> 16);
    pos[2] = t0 + t1 + (ex1 & 0xffffu);
    pos[3] = t0 + t1 + t2 + (ex1 >> 16);
#pragma unroll
    for (int j = 0; j < EPT; ++j) {
      uint32_t d2 = (uint32_t)(e[j] >> (32 + 8 * P + 2 * rnd)) & 3u;
      nxt[SIDX(pos[d2]++)] = e[j];
    }
    __syncthreads();
    uint64_t* tmp = cur; cur = nxt; nxt = tmp;
  }
  // cur == bufA: tile stably sorted by digit P

  // digit histogram (order-invariant; e[] holds the tile's elements)
#pragma unroll
  for (int j = 0; j < EPT; ++j)
    atomicAdd(&ldsHist[(uint32_t)(e[j] >> (32 + 8 * P)) & 255u], 1u);
  __syncthreads();
  const uint32_t agg = ldsHist[t];

  // local exclusive starts per digit
  {
    const int lane = t & 63, w = t >> 6;
    uint32_t s = agg;
#pragma unroll
    for (int o = 1; o < 64; o <<= 1) {
      uint32_t n = __shfl_up(s, (unsigned)o, 64);
      if (lane >= o) s += n;
    }
    if (lane == 63) scanS[8 + w] = s;
    __syncthreads();
    if (t == 0) {
      uint32_t a = 0;
#pragma unroll
      for (int i = 0; i < 4; ++i) { uint32_t q = scanS[8 + i]; scanS[8 + i] = a; a += q; }
    }
    __syncthreads();
    ldsStart[t] = s - agg + scanS[8 + w];
  }
  // global base: per-pass digit CDF + per-bin prefix over preceding blocks
  ldsBase[t] = gh[((size_t)sl * 4 + P) * 256 + t] +
               Hkb[(size_t)sl * HL + (size_t)blk * RADIX + t];
  __syncthreads();

  // emit in sorted-tile order: digit runs -> contiguous global ranges
#pragma unroll
  for (int r = 0; r < EPT; ++r) {
    uint32_t s = (uint32_t)(r * 256 + t);
    uint64_t el = cur[SIDX(s)];
    uint32_t d = (uint32_t)(el >> (32 + 8 * P)) & 255u;
    uint32_t dest = ldsBase[d] + s - ldsStart[d];
    if (MODE == 0) {
      dst[(size_t)sl * SEG_N + dest] = el;
    } else if (MODE == 1) {
      tsorted[dest] = finv((uint32_t)(el >> 32));
    } else {
      out[(size_t)(seg - 1) * SEG_N + (uint32_t)el] = tsorted[dest];
    }
  }
}

// ---------------------------------------------------------------------------
extern "C" void kernel_launch(void* const* d_in, const int* in_sizes, int n_in,
                              void* d_out, int out_size, void* d_ws, size_t ws_size,
                              hipStream_t stream) {
  const float* x = (const float*)d_in[0];
  const float* tmpl = (const float*)d_in[1];
  float* out = (float*)d_out;

  auto needB = [](int nb) -> size_t {
    return (size_t)nb * ((size_t)SEG_N * 16 + (size_t)HL * 4 + 4096 + 1024) +
           (size_t)SEG_N * 4 + 65536;
  };
  const int nb = (ws_size >= needB(9)) ? 9 : (ws_size >= needB(3)) ? 3 : 1;

  uint8_t* w = (uint8_t*)d_ws;
  size_t off = 0;
  auto carve = [&](size_t bytes) -> void* {
    void* p = w + off;
    off = (off + bytes + 255) & ~(size_t)255;
    return p;
  };
  uint64_t* pairsA = (uint64_t*)carve((size_t)nb * SEG_N * 8);
  uint64_t* pairsB = (uint64_t*)carve((size_t)nb * SEG_N * 8);
  uint32_t* Hkb = (uint32_t*)carve((size_t)nb * HL * 4);
  uint32_t* gh = (uint32_t*)carve((size_t)nb * 1024 * 4);
  float* tsorted = (float*)carve((size_t)SEG_N * 4);

  for (int g = 0; g < NSEG; g += nb) {
    const dim3 gi(NBLK, nb);
    const dim3 gb(RADIX, nb);

    hipMemsetAsync(gh, 0, (size_t)nb * 1024 * 4, stream);
    init_k<<<gi, 256, 0, stream>>>(x, tmpl, g, pairsA, Hkb, gh);
    cdf_k<<<dim3(4, nb), 256, 0, stream>>>(gh);

    // pass 0 (hist fused into init)
    binscan_k<<<gb, 256, 0, stream>>>(Hkb);
    part_k<0, 0><<<gi, 256, 0, stream>>>(pairsA, pairsB, Hkb, gh, tsorted, out, g, 0);
    // pass 1
    hist_k<<<gi, 256, 0, stream>>>(pairsB, Hkb, 1);
    binscan_k<<<gb, 256, 0, stream>>>(Hkb);
    part_k<1, 0><<<gi, 256, 0, stream>>>(pairsB, pairsA, Hkb, gh, tsorted, out, g, 0);
    // pass 2
    hist_k<<<gi, 256, 0, stream>>>(pairsA, Hkb, 2);
    binscan_k<<<gb, 256, 0, stream>>>(Hkb);
    part_k<2, 0><<<gi, 256, 0, stream>>>(pairsA, pairsB, Hkb, gh, tsorted, out, g, 0);
    // pass 3 (fused epilogue)
    hist_k<<<gi, 256, 0, stream>>>(pairsB, Hkb, 3);
    binscan_k<<<gb, 256, 0, stream>>>(Hkb);
    if (g == 0) {
      part_k<3, 1><<<dim3(NBLK, 1), 256, 0, stream>>>(pairsB, pairsA, Hkb, gh,
                                                      tsorted, out, g, 0);
      if (nb > 1)
        part_k<3, 2><<<dim3(NBLK, nb - 1), 256, 0, stream>>>(pairsB, pairsA, Hkb,
                                                             gh, tsorted, out, g, 1);
    } else {
      part_k<3, 2><<<dim3(NBLK, nb), 256, 0, stream>>>(pairsB, pairsA, Hkb, gh,
                                                       tsorted, out, g, 0);
    }
  }
}